// Round 5
// baseline (227.806 us; speedup 1.0000x reference)
//
#include <hip/hip_runtime.h>
#include <float.h>

#define H 64
#define W 512
#define L2E 1.4426950408889634f

// ws layout (floats)
#define WS_DISPT 0         // disp_r2l_ini [64][512]   (from tril/cost2)
#define WS_DISPU 32768     // disp_l2r_ini [64][512]   (from triu/cost1)
#define WS_AEXP  65536     // aL2E [tn][h][i]  (att = exp2(c*L2E - a))
#define WS_PART  131072    // colsum partials [tn][h][qb(4)][512]

// ---------------------------------------------------------------------------
// Pass A: per-row softmax stats, quarter-row per thread, branchless online
// scan (R4 lesson: no runtime branches around register arrays; R3 lesson:
// stay under the 64-VGPR cliff -> launch_bounds(256,8)).
// Thread owns j in [q*128, q*128+128), 8 chunks of 16. Tracks running
// (m, s, ws) online-softmax style plus argmax (best, bj) with neighbor
// values vp=c[bj-1], vn=c[bj+1] via rolling selects (static indices only).
// 2-round xor merge across the 4 lanes of a row; boundary neighbor fixups
// use carried first/last element values. Outputs: disp_ini, raw (3-tap
// subpixel, taps are exp2 of vp/best/vn), and a = mx*L2E + log2(s+1e-8)
// so pass B can compute att = exp2(c*L2E - a) directly.
// lower (tn==0, cost2/tril): valid j<=i, pos=(i-j)*pscale -> out ch2
// upper (tn==1, cost1/triu): valid j>=i, pos=(j-i)*pscale -> out ch3
// ---------------------------------------------------------------------------
__global__ __launch_bounds__(256, 8) void row_stats(
    const float* __restrict__ cost1, const float* __restrict__ cost2,
    float* __restrict__ ws, float* __restrict__ out)
{
  const int g   = blockIdx.x * 256 + threadIdx.x;   // 262144 threads
  const int row = g >> 2;                           // [0, 65536)
  const int q   = g & 3;                            // quarter
  const int tn  = row & 1;                          // interleave tensors
  const int rr  = row >> 1;
  const int h   = rr >> 9;
  const int i   = rr & 511;
  const bool lower = (tn == 0);
  const float* base = (lower ? cost2 : cost1) + ((size_t)h * W + i) * W + q * 128;
  const int j0 = q * 128;

  float m = -FLT_MAX, s = 0.f, w = 0.f;
  float best = -FLT_MAX, vp = -FLT_MAX, vn = -FLT_MAX;
  int   bj = 0;
  float firstV = 0.f, lastprev = -FLT_MAX;
  bool  pend = false;

  for (int cc = 0; cc < 8; cc++) {
    float c[16];
    const float4* p4 = (const float4*)(base + cc * 16);
    #pragma unroll
    for (int t = 0; t < 4; t++) {
      const float4 v = p4[t];
      c[t*4+0]=v.x; c[t*4+1]=v.y; c[t*4+2]=v.z; c[t*4+3]=v.w;
    }
    const int jc = j0 + cc * 16;
    // mask invalid -> -FLT_MAX (branchless)
    #pragma unroll
    for (int k = 0; k < 16; k++) {
      const int j = jc + k;
      const bool v = lower ? (j <= i) : (j >= i);
      c[k] = v ? c[k] : -FLT_MAX;
    }
    if (cc == 0) firstV = c[0];
    vn = pend ? c[0] : vn;        // argmax was at previous chunk's last elem
    pend = false;
    // chunk max (tree, for online rescale)
    float cm = c[0];
    #pragma unroll
    for (int k = 1; k < 16; k++) cm = fmaxf(cm, c[k]);
    // rolling argmax with neighbor tracking (all static indices)
    #pragma unroll
    for (int k = 0; k < 16; k++) {
      const bool upd = c[k] > best;
      if (upd) {
        best = c[k]; bj = jc + k;
        vp = (k == 0) ? lastprev : c[k-1];
        if (k < 15) vn = c[k+1]; else pend = true;
      }
    }
    lastprev = c[15];
    // chunk exp-sums relative to cm
    float cs = 0.f, cw = 0.f;
    #pragma unroll
    for (int k = 0; k < 16; k++) {
      const float e = exp2f((c[k] - cm) * L2E);
      cs += e;
      cw = fmaf((float)k, e, cw);
    }
    cw = fmaf((float)jc, cs, cw);
    // online merge into running stats
    const float mn = fmaxf(m, cm);
    const float fa = exp2f((m - mn) * L2E);
    const float fb = exp2f((cm - mn) * L2E);
    s = s * fa + cs * fb;
    w = w * fa + cw * fb;
    m = mn;
  }
  float lastV = lastprev;

  // merge the 4 quarter-lanes of this row (2 xor rounds)
  #pragma unroll
  for (int off = 1; off <= 2; off <<= 1) {
    const float om = __shfl_xor(m, off);
    const float os = __shfl_xor(s, off);
    const float ow = __shfl_xor(w, off);
    const float ob = __shfl_xor(best, off);
    const int   oj = __shfl_xor(bj, off);
    const float ovp = __shfl_xor(vp, off);
    const float ovn = __shfl_xor(vn, off);
    const float ofv = __shfl_xor(firstV, off);
    const float olv = __shfl_xor(lastV, off);
    const float mn = fmaxf(m, om);
    const float fa = exp2f((m - mn) * L2E);
    const float fb = exp2f((om - mn) * L2E);
    s = s * fa + os * fb;
    w = w * fa + ow * fb;
    m = mn;
    const bool hi = (q & off) != 0;          // my segment is higher-j side
    const int pj0 = (q & ~(2 * off - 1)) * 128;
    const int alj = pj0 + off * 128 - 1;     // A(lower side) last j
    const int bfj = alj + 1;                 // B(higher side) first j
    const float Ab = hi ? ob : best, Bb = hi ? best : ob;
    const int   Aj = hi ? oj : bj,   Bj = hi ? bj : oj;
    const float Avp = hi ? ovp : vp, Bvp = hi ? vp : ovp;
    const float Avn = hi ? ovn : vn, Bvn = hi ? vn : ovn;
    const float Afv = hi ? ofv : firstV, Bfv = hi ? firstV : ofv;
    const float Alv = hi ? olv : lastV,  Blv = hi ? lastV : olv;
    const bool tb = Bb > Ab;                 // ties -> lower j (first occ.)
    best = tb ? Bb : Ab;
    bj   = tb ? Bj : Aj;
    vp   = tb ? ((Bj == bfj) ? Alv : Bvp) : Avp;
    vn   = tb ? Bvn : ((Aj == alj) ? Bfv : Avn);
    firstV = Afv; lastV = Blv;
  }

  if (q == 0) {
    const float pscale = 2.0f / 511.0f;
    const bool hasMasked = lower ? (i < W - 1) : (i > 0);
    const float mx = hasMasked ? fmaxf(m, 0.f) : m;   // masked zeros join max
    const float fsc = exp2f((m - mx) * L2E);
    s *= fsc; w *= fsc;
    const float inv = 1.f / (s + 1e-8f);
    float* disp = ws + (lower ? WS_DISPT : WS_DISPU);
    disp[(h << 9) + i] = (float)i - w * inv;
    ws[WS_AEXP + (tn << 15) + (h << 9) + i] = fmaf(mx, L2E, log2f(s + 1e-8f));
    // 3-tap subpixel raw disparity
    const float e_h = fsc;                             // exp(best - mx)
    const float e_p = exp2f((vp - mx) * L2E);          // 0 if vp masked/pad
    const float e_n = exp2f((vn - mx) * L2E);
    const float t0 = e_p + e_h + e_n;
    const float fb = (float)bj;
    const float w0 = fmaf(e_p, fb - 1.f, fmaf(e_h, fb, e_n * (fb + 1.f)));
    const float fi = (float)i;
    const float t1 = pscale * (lower ? (fi * t0 - w0) : (w0 - fi * t0));
    const float n0 = t0 * inv;
    float* raw = out + (lower ? 2 : 3) * (H * W);
    raw[(h << 9) + i] = (t1 * inv) / (n0 < 0.1f ? 1.f : n0);
  }
}

// ---------------------------------------------------------------------------
// Pass B: column sums. Block = (tn, h, row-quarter qb). 512 threads =
// 4 rowgroups x 128 col-threads (4 cols each, float4). Fully coalesced
// streaming re-read (L3-resident after pass A); att = exp2(c*L2E - a_row),
// masked to the triangle; per-thread register accumulation -> LDS combine
// -> per-block partial written to ws (no atomics, no memset).
// ---------------------------------------------------------------------------
__global__ __launch_bounds__(512) void col_sums(
    const float* __restrict__ cost1, const float* __restrict__ cost2,
    float* __restrict__ ws)
{
  __shared__ float sa[128];
  __shared__ float sc[4][516];
  const int bb = blockIdx.x;               // 512 blocks
  const int tn = bb & 1;
  const int rest = bb >> 1;
  const int h  = rest >> 2;
  const int qb = rest & 3;
  const bool lower = (tn == 0);
  const float* base = (lower ? cost2 : cost1) + (size_t)h * W * W;
  const int tid = threadIdx.x;
  const int rg = tid >> 7;                 // rowgroup 0..3 (32 rows each)
  const int ct = tid & 127;
  const int jj = ct * 4;

  if (tid < 128) sa[tid] = ws[WS_AEXP + (tn << 15) + (h << 9) + qb * 128 + tid];
  __syncthreads();

  float4 acc = {0.f, 0.f, 0.f, 0.f};
  const int r0 = qb * 128 + rg * 32;
  #pragma unroll 4
  for (int t = 0; t < 32; t++) {
    const int r = r0 + t;
    const float a = sa[rg * 32 + t];
    const float4 v = *(const float4*)(base + (size_t)r * W + jj);
    const float x0 = exp2f(fmaf(v.x, L2E, -a));
    const float x1 = exp2f(fmaf(v.y, L2E, -a));
    const float x2 = exp2f(fmaf(v.z, L2E, -a));
    const float x3 = exp2f(fmaf(v.w, L2E, -a));
    if (lower) {   // valid j <= r
      acc.x += (jj     <= r) ? x0 : 0.f;
      acc.y += (jj + 1 <= r) ? x1 : 0.f;
      acc.z += (jj + 2 <= r) ? x2 : 0.f;
      acc.w += (jj + 3 <= r) ? x3 : 0.f;
    } else {       // valid j >= r
      acc.x += (jj     >= r) ? x0 : 0.f;
      acc.y += (jj + 1 >= r) ? x1 : 0.f;
      acc.z += (jj + 2 >= r) ? x2 : 0.f;
      acc.w += (jj + 3 >= r) ? x3 : 0.f;
    }
  }
  *(float4*)&sc[rg][jj] = acc;
  __syncthreads();
  if (tid < 512) {
    const float p = sc[0][tid] + sc[1][tid] + sc[2][tid] + sc[3][tid];
    ws[WS_PART + (((tn * H + h) * 4 + qb) << 9) + tid] = p;
  }
}

// ---------------------------------------------------------------------------
// Closed-form hole fill (the W-step scan converges to this):
//   valid i            -> disp_ini[i]
//   invalid, valid p<i -> disp_ini[p] * (1+1e-4)^-(i-p)
//   invalid prefix     -> disp_ini[p0] * (1+1e-4)^-(p0-i)
//   no valid in row    -> 0
// One wave per (pair, h) row. Combines the 4 colsum partials inline.
// Pairing per reference: ch0 = regress(att_r2l, vm_left[from triu/cost1]);
//                        ch1 = regress(att_l2r, vm_right[from tril/cost2]).
// ---------------------------------------------------------------------------
__global__ __launch_bounds__(64) void fill_rows(
    const float* __restrict__ ws, float* __restrict__ out)
{
  __shared__ float xrow[W];
  const int pair = blockIdx.x >> 6;   // 0: ch0, 1: ch1
  const int h    = blockIdx.x & 63;
  const float* dsp = ws + (pair ? WS_DISPU : WS_DISPT) + h * W;
  const int cstn = pair ? 0 : 1;      // swap: vm comes from the OTHER tensor
  const float* pb = ws + WS_PART + (((cstn * H + h) * 4) << 9);
  float* o = out + pair * (H * W) + h * W;
  const int lane = threadIdx.x;
  const int j0 = lane * 8;

  float x[8];
  bool mvals[8];
  int incl[8];
  int run = -1, fv = W;
  #pragma unroll
  for (int k = 0; k < 8; k++) {
    const int jj = j0 + k;
    x[k] = dsp[jj];
    const float cs = pb[jj] + pb[512 + jj] + pb[1024 + jj] + pb[1536 + jj];
    mvals[k] = cs > 0.1f;
    xrow[jj] = x[k];
    if (mvals[k]) { run = jj; if (fv == W) fv = jj; }
    incl[k] = run;
  }
  int v = run;
  #pragma unroll
  for (int off = 1; off < 64; off <<= 1) {
    const int tv = __shfl_up(v, off);
    if (lane >= off) v = max(v, tv);
  }
  int excl = __shfl_up(v, 1);
  if (lane == 0) excl = -1;
  int p0 = fv;
  #pragma unroll
  for (int off = 32; off; off >>= 1) p0 = min(p0, __shfl_xor(p0, off));
  __syncthreads();

  const float C2 = -1.4426229e-4f;  // -log2(1 + 1e-4)
  #pragma unroll
  for (int k = 0; k < 8; k++) {
    const int jj = j0 + k;
    float ov;
    if (mvals[k]) {
      ov = x[k];
    } else {
      const int p = max(excl, incl[k]);
      if (p >= 0)        ov = xrow[p]  * exp2f(C2 * (float)(jj - p));
      else if (p0 < W)   ov = xrow[p0] * exp2f(C2 * (float)(p0 - jj));
      else               ov = 0.f;
    }
    o[jj] = ov;
  }
}

extern "C" void kernel_launch(void* const* d_in, const int* in_sizes, int n_in,
                              void* d_out, int out_size, void* d_ws, size_t ws_size,
                              hipStream_t stream) {
  const float* cost1 = (const float*)d_in[0];  // -> att_l2r (triu)
  const float* cost2 = (const float*)d_in[1];  // -> att_r2l (tril)
  float* out = (float*)d_out;                  // [4, H, W]
  float* ws = (float*)d_ws;                    // 393216 floats = 1.5 MB used

  row_stats<<<1024, 256, 0, stream>>>(cost1, cost2, ws, out);
  col_sums<<<512, 512, 0, stream>>>(cost1, cost2, ws);
  fill_rows<<<2 * H, 64, 0, stream>>>(ws, out);
}

// Round 6
// 170.805 us; speedup vs baseline: 1.3337x; 1.3337x over previous
//
#include <hip/hip_runtime.h>
#include <float.h>

#define H 64
#define W 512
#define SPLIT 8   // blocks per (tensor,h): 2*64*8 = 1024 blocks

// ---------------------------------------------------------------------------
// Fused masked-exp-norm row statistics for BOTH cost volumes in one dispatch.
// R2 structure (proven no-spill: c[8] float4 loads, straight-line phases,
// wave-per-row, VGPR 32) + ROW-PAIR ILP: each wave iteration processes 2
// adjacent rows with phase-interleaved code so the two dependent shuffle
// chains (the latency bottleneck, VALUBusy was 42%) dual-issue.
// R3/R4/R5 lessons: no runtime branches around register arrays, no big
// per-thread arrays, stay under the VGPR cliff -> launch_bounds(512,6).
// Per row i, without materializing att:
//   disp_ini[i] = i - sum_j att[i,j]*j
//   colsum[j]  += sum_i att[i,j]     (LDS -> global atomics, cs pre-zeroed)
//   raw[i]      = 3-tap subpixel around argmax, via
//                 t1 = pscale*(i*t0 - w0)  [tril]  /  pscale*(w0 - i*t0) [triu]
// lower=true  (cost2/tril, valid j<=i) -> disp_r2l, cs_r2l, out ch2
// lower=false (cost1/triu, valid j>=i) -> disp_l2r, cs_l2r, out ch3
// Masked elements are set to -FLT_MAX so exp()->0 (no per-element selects in
// phase 2); argmax fused into the max butterfly (first occurrence on ties).
// ---------------------------------------------------------------------------
__global__ __launch_bounds__(512, 6) void attn_stats_all(
    const float* __restrict__ cost1, const float* __restrict__ cost2,
    float* __restrict__ disp_r2l, float* __restrict__ disp_l2r,
    float* __restrict__ cs_r2l,  float* __restrict__ cs_l2r,
    float* __restrict__ out)
{
  __shared__ float scol[W];
  const int tid  = threadIdx.x;
  const int lane = tid & 63;
  const int wid  = tid >> 6;              // 0..7
  const int gid  = blockIdx.x;
  const bool lower = (gid & 1) == 0;      // interleave tensors across CUs/XCDs
  const int rest = gid >> 1;
  const int h    = rest / SPLIT;
  const int s    = rest % SPLIT;

  const float* cost = lower ? cost2 : cost1;
  float* disp = lower ? disp_r2l : disp_l2r;
  float* csum = lower ? cs_r2l  : cs_l2r;
  float* raw  = out + (lower ? 2 : 3) * (H * W);

  scol[tid] = 0.f;
  __syncthreads();

  float cacc[8] = {0,0,0,0,0,0,0,0};
  const float pscale = 2.0f / 511.0f;     // linspace(0,2,512) step
  const float* hb = cost + (size_t)h * W * W;

  int jmap[8];
  #pragma unroll
  for (int k = 0; k < 8; k++)
    jmap[k] = (k < 4) ? (lane * 4 + k) : (256 + lane * 4 + (k - 4));

  for (int it = 0; it < 4; it++) {        // 2 rows per iteration
    int   i[2];
    float c[2][8];
    #pragma unroll
    for (int r = 0; r < 2; r++) {
      i[r] = s * 64 + wid * 8 + it * 2 + r;
      const float* rp = hb + (size_t)i[r] * W;
      const float4 va = ((const float4*)rp)[lane];       // j = lane*4+k
      const float4 vb = ((const float4*)rp)[64 + lane];  // j = 256+lane*4+(k-4)
      c[r][0]=va.x; c[r][1]=va.y; c[r][2]=va.z; c[r][3]=va.w;
      c[r][4]=vb.x; c[r][5]=vb.y; c[r][6]=vb.z; c[r][7]=vb.w;
    }

    // ---- mask -> -FLT_MAX; local max+argmax (first occurrence, j ascending)
    float best[2] = {-FLT_MAX, -FLT_MAX};
    int   bj[2]   = {1024, 1024};
    #pragma unroll
    for (int r = 0; r < 2; r++) {
      #pragma unroll
      for (int k = 0; k < 8; k++) {
        const int j = jmap[k];
        const bool vld = lower ? (j <= i[r]) : (j >= i[r]);
        const float v = vld ? c[r][k] : -FLT_MAX;
        c[r][k] = v;
        if (v > best[r]) { best[r] = v; bj[r] = j; }
      }
    }
    // ---- interleaved max/argmax butterflies (2 independent chains)
    #pragma unroll
    for (int off = 32; off; off >>= 1) {
      #pragma unroll
      for (int r = 0; r < 2; r++) {
        const float ov = __shfl_xor(best[r], off);
        const int   oj = __shfl_xor(bj[r], off);
        if (ov > best[r] || (ov == best[r] && oj < bj[r])) { best[r] = ov; bj[r] = oj; }
      }
    }

    float mx[2];
    #pragma unroll
    for (int r = 0; r < 2; r++) {
      const bool hasMasked = lower ? (i[r] < W - 1) : (i[r] > 0);
      mx[r] = hasMasked ? fmaxf(best[r], 0.f) : best[r];  // masked zeros join max
    }

    // ---- exp + per-lane sums (c[] overwritten with e; masked -> exp(-inf)=0)
    float ssum[2] = {0,0}, wsum[2] = {0,0}, s0[2] = {0,0}, w0[2] = {0,0};
    #pragma unroll
    for (int r = 0; r < 2; r++) {
      #pragma unroll
      for (int k = 0; k < 8; k++) {
        const int j = jmap[k];
        const float e = __expf(c[r][k] - mx[r]);
        c[r][k] = e;
        const float p = e * (float)j;
        ssum[r] += e; wsum[r] += p;
        if ((unsigned)(j - (bj[r] - 1)) <= 2u) { s0[r] += e; w0[r] += p; }
      }
    }
    // ---- interleaved sum butterflies
    #pragma unroll
    for (int off = 32; off; off >>= 1) {
      #pragma unroll
      for (int r = 0; r < 2; r++) {
        ssum[r] += __shfl_xor(ssum[r], off);
        wsum[r] += __shfl_xor(wsum[r], off);
      }
    }

    #pragma unroll
    for (int r = 0; r < 2; r++) {
      const float inv = 1.f / (ssum[r] + 1e-8f);
      // 3-tap gather: taps around uniform hi live in <=2 known lanes
      const int hi = bj[r];
      const int jlo = hi > 0 ? hi - 1 : 0;
      const int jh2 = hi < W - 1 ? hi + 1 : W - 1;
      const int l1 = (jlo & 255) >> 2;
      const int l2 = (jh2 & 255) >> 2;
      float t0 = __shfl(s0[r], l1), w0g = __shfl(w0[r], l1);
      if (l2 != l1) { t0 += __shfl(s0[r], l2); w0g += __shfl(w0[r], l2); }

      #pragma unroll
      for (int k = 0; k < 8; k++) cacc[k] += c[r][k] * inv;

      if (lane == 0) {
        const float fi = (float)i[r];
        disp[h * W + i[r]] = fi - wsum[r] * inv;
        const float n0 = t0 * inv;                      // sum of the 3 att taps
        const float t1 = pscale * (lower ? (fi * t0 - w0g) : (w0g - fi * t0));
        raw[h * W + i[r]] = (t1 * inv) / (n0 < 0.1f ? 1.f : n0);
      }
    }
  }

  // colsum: regs -> LDS atomics (8-wave combine) -> global atomics
  #pragma unroll
  for (int k = 0; k < 8; k++) atomicAdd(&scol[jmap[k]], cacc[k]);
  __syncthreads();
  atomicAdd(&csum[h * W + tid], scol[tid]);
}

// ---------------------------------------------------------------------------
// Closed-form hole fill (the W-step scan converges to this):
//   valid i            -> disp_ini[i]
//   invalid, valid p<i -> disp_ini[p] * (1+1e-4)^-(i-p)   (left-to-right pass)
//   invalid prefix     -> disp_ini[p0] * (1+1e-4)^-(p0-i) (right-to-left pass)
//   no valid in row    -> 0
// One wave per (pair, h) row.
// ---------------------------------------------------------------------------
__global__ __launch_bounds__(64) void fill_rows(
    const float* __restrict__ dispA, const float* __restrict__ csA,
    const float* __restrict__ dispB, const float* __restrict__ csB,
    float* __restrict__ out)
{
  __shared__ float xrow[W];
  const int pair = blockIdx.x >> 6;   // 0: ch0 (r2l disp, vm_left), 1: ch1
  const int h    = blockIdx.x & 63;
  const float* dsp = (pair ? dispB : dispA) + h * W;
  const float* cs  = (pair ? csB  : csA ) + h * W;
  float* o = out + pair * (H * W) + h * W;
  const int lane = threadIdx.x;
  const int j0 = lane * 8;

  float x[8];
  bool m[8];
  int incl[8];
  int run = -1, fv = W;
  #pragma unroll
  for (int k = 0; k < 8; k++) {
    x[k] = dsp[j0 + k];
    m[k] = cs[j0 + k] > 0.1f;
    xrow[j0 + k] = x[k];
    if (m[k]) { run = j0 + k; if (fv == W) fv = j0 + k; }
    incl[k] = run;
  }
  // inclusive max-scan across lanes of "last valid index in my segment"
  int v = run;
  #pragma unroll
  for (int off = 1; off < 64; off <<= 1) {
    const int tv = __shfl_up(v, off);
    if (lane >= off) v = max(v, tv);
  }
  int excl = __shfl_up(v, 1);
  if (lane == 0) excl = -1;
  // first valid index in the whole row
  int p0 = fv;
  #pragma unroll
  for (int off = 32; off; off >>= 1) p0 = min(p0, __shfl_xor(p0, off));
  __syncthreads();

  const float C2 = -1.4426229e-4f;  // -log2(1 + 1e-4)
  #pragma unroll
  for (int k = 0; k < 8; k++) {
    const int jj = j0 + k;
    float ov;
    if (m[k]) {
      ov = x[k];
    } else {
      const int p = max(excl, incl[k]);
      if (p >= 0)        ov = xrow[p]  * exp2f(C2 * (float)(jj - p));
      else if (p0 < W)   ov = xrow[p0] * exp2f(C2 * (float)(p0 - jj));
      else               ov = 0.f;
    }
    o[jj] = ov;
  }
}

extern "C" void kernel_launch(void* const* d_in, const int* in_sizes, int n_in,
                              void* d_out, int out_size, void* d_ws, size_t ws_size,
                              hipStream_t stream) {
  const float* cost1 = (const float*)d_in[0];  // -> att_l2r (triu)
  const float* cost2 = (const float*)d_in[1];  // -> att_r2l (tril)
  float* out = (float*)d_out;                  // [4, H, W]
  float* w = (float*)d_ws;
  float* disp_r2l_ini = w;                     // 32768 floats (from cost2)
  float* disp_l2r_ini = w + 32768;             // (from cost1)
  float* cs_l2r       = w + 65536;             // colsums of att_l2r -> vm_left
  float* cs_r2l       = w + 98304;             // colsums of att_r2l -> vm_right

  hipMemsetAsync(cs_l2r, 0, 2 * (size_t)H * W * sizeof(float), stream);

  attn_stats_all<<<2 * H * SPLIT, 512, 0, stream>>>(
      cost1, cost2, disp_r2l_ini, disp_l2r_ini, cs_r2l, cs_l2r, out);

  // ch0 = regress(att_r2l, vm_left); ch1 = regress(att_l2r, vm_right)
  fill_rows<<<2 * H, 64, 0, stream>>>(disp_r2l_ini, cs_l2r,
                                      disp_l2r_ini, cs_r2l, out);
}

// Round 7
// 163.133 us; speedup vs baseline: 1.3964x; 1.0470x over previous
//
#include <hip/hip_runtime.h>
#include <float.h>

#define H 64
#define W 512
#define SPLIT 8   // blocks per (tensor,h): 2*64*8 = 1024 blocks

// ---------------------------------------------------------------------------
// Fused masked-exp-norm row statistics for BOTH cost volumes, triangle-aware.
// R2's proven no-spill shape (wave-per-row, c[8] float4 loads, straight-line
// phases) + two work cuts:
//  1) Coarse triangle skip: tril rows <256 and triu rows >=256 only touch one
//     256-column half -> NH=1 template instantiation (half the loads/exps).
//     Selected by a BLOCK-UNIFORM branch over compile-time instantiations --
//     no conditional register-array defs (R4 spill lesson), no forced
//     launch_bounds min-waves (R5 spill lesson).
//  2) 3-tap subpixel (gen_raw_disp) no longer tracked per element: after the
//     argmax butterfly, c[bj-1]/c[bj+1] are reloaded via two wave-uniform
//     L2-hot loads issued early (overlap the exp phase), taps computed in the
//     epilogue with triangle-validity flags (matches reference zero-padding).
// Per row i, without materializing att:
//   disp_ini[i] = i - sum_j att[i,j]*j
//   colsum[j]  += sum_i att[i,j]     (LDS -> global atomics, cs pre-zeroed)
//   raw[i]      = 3-tap subpixel: t1 = pscale*(i*t0-w0) [tril] /
//                                      pscale*(w0-i*t0) [triu]
// lower (cost2/tril, valid j<=i) -> disp_r2l, cs_r2l, out ch2
// upper (cost1/triu, valid j>=i) -> disp_l2r, cs_l2r, out ch3
// Masked elements -> -FLT_MAX so exp()->0; masked zeros join the row max
// whenever the row has any masked element; argmax = first occurrence.
// ---------------------------------------------------------------------------
template<bool LOWER, bool FULLROW>
__device__ __forceinline__ void process_rows(
    const float* __restrict__ hb, const int h, const int s,
    const int lane, const int wid,
    float* __restrict__ disp, float* __restrict__ raw, float* scol)
{
  constexpr int NH = FULLROW ? 2 : 1;                 // 256-col halves touched
  constexpr int JB = FULLROW ? 0 : (LOWER ? 0 : 256); // base column
  const float pscale = 2.0f / 511.0f;                 // linspace(0,2,512) step

  float cacc[NH * 4];
  #pragma unroll
  for (int q = 0; q < NH * 4; q++) cacc[q] = 0.f;

  int   jmap[NH * 4];
  float jfmap[NH * 4];
  #pragma unroll
  for (int hh = 0; hh < NH; hh++)
    #pragma unroll
    for (int k = 0; k < 4; k++) {
      jmap[hh * 4 + k]  = JB + hh * 256 + lane * 4 + k;
      jfmap[hh * 4 + k] = (float)jmap[hh * 4 + k];
    }

  for (int t = wid; t < 64; t += 8) {
    const int i = s * 64 + t;
    const float fi = (float)i;
    const float* rp = hb + (size_t)i * W;

    float c[NH * 4];
    #pragma unroll
    for (int hh = 0; hh < NH; hh++) {
      const float4 v = ((const float4*)rp)[(JB >> 2) + hh * 64 + lane];
      c[hh*4+0] = v.x; c[hh*4+1] = v.y; c[hh*4+2] = v.z; c[hh*4+3] = v.w;
    }

    // ---- phase 1: mask (diagonal half only) + max + argmax (first occ.)
    float best = -FLT_MAX;
    int   bj   = 1024;
    #pragma unroll
    for (int hh = 0; hh < NH; hh++) {
      // which half can contain masked elements (compile-time per hh)
      const bool NM = FULLROW ? (LOWER ? (hh == 1) : (hh == 0)) : true;
      #pragma unroll
      for (int k = 0; k < 4; k++) {
        const int q = hh * 4 + k;
        float v = c[q];
        if (NM) {
          const bool vld = LOWER ? (jmap[q] <= i) : (jmap[q] >= i);
          v = vld ? v : -FLT_MAX;
          c[q] = v;
        }
        if (v > best) { best = v; bj = jmap[q]; }   // j ascending in (hh,k)
      }
    }
    #pragma unroll
    for (int off = 32; off; off >>= 1) {
      const float ov = __shfl_xor(best, off);
      const int   oj = __shfl_xor(bj, off);
      if (ov > best || (ov == best && oj < bj)) { best = ov; bj = oj; }
    }

    // ---- issue tap reloads early (wave-uniform, L2-hot; overlap exp phase)
    const int bjm = bj - 1, bjp = bj + 1;
    const int am = min(max(bjm, 0), W - 1);
    const int ap = min(bjp, W - 1);
    const float cm_ = rp[am];
    const float cp_ = rp[ap];

    const bool hasMasked = LOWER ? (i < W - 1) : (i > 0);
    const float mx = hasMasked ? fmaxf(best, 0.f) : best;  // zeros join max

    // ---- phase 2: exp + sums (c[] overwritten with e; masked -> 0)
    float ssum = 0.f, wsum = 0.f;
    #pragma unroll
    for (int q = 0; q < NH * 4; q++) {
      const float e = __expf(c[q] - mx);
      c[q] = e;
      ssum += e;
      wsum = fmaf(e, jfmap[q], wsum);
    }
    #pragma unroll
    for (int off = 32; off; off >>= 1) {
      ssum += __shfl_xor(ssum, off);
      wsum += __shfl_xor(wsum, off);
    }
    const float inv = 1.f / (ssum + 1e-8f);

    #pragma unroll
    for (int q = 0; q < NH * 4; q++) cacc[q] = fmaf(c[q], inv, cacc[q]);

    if (lane == 0) {
      // 3-tap subpixel: validity per reference zero-padded triangle gather
      const bool pv = LOWER ? (bjm >= 0) : (bjm >= i);
      const bool nv = LOWER ? (bjp <= i) : (bjp <= W - 1);
      const float e_h = __expf(best - mx);
      const float e_p = pv ? __expf(cm_ - mx) : 0.f;
      const float e_n = nv ? __expf(cp_ - mx) : 0.f;
      const float t0 = e_p + e_h + e_n;
      const float w0 = fmaf(e_p, (float)bjm, fmaf(e_h, (float)bj, e_n * (float)bjp));
      disp[h * W + i] = fi - wsum * inv;
      const float n0 = t0 * inv;                       // sum of the 3 att taps
      const float t1 = pscale * (LOWER ? (fi * t0 - w0) : (w0 - fi * t0));
      raw[h * W + i] = (t1 * inv) / (n0 < 0.1f ? 1.f : n0);
    }
  }

  // colsum partials: regs -> LDS atomics (8-wave combine)
  #pragma unroll
  for (int q = 0; q < NH * 4; q++) atomicAdd(&scol[jmap[q]], cacc[q]);
}

__global__ __launch_bounds__(512) void attn_stats_all(
    const float* __restrict__ cost1, const float* __restrict__ cost2,
    float* __restrict__ disp_r2l, float* __restrict__ disp_l2r,
    float* __restrict__ cs_r2l,  float* __restrict__ cs_l2r,
    float* __restrict__ out)
{
  __shared__ float scol[W];
  const int tid  = threadIdx.x;
  const int lane = tid & 63;
  const int wid  = tid >> 6;              // 0..7
  const int gid  = blockIdx.x;
  const bool lower = (gid & 1) == 0;      // interleave tensors across CUs/XCDs
  const int rest = gid >> 1;
  const int h    = rest >> 3;
  const int s    = rest & 7;              // row block: rows [s*64, s*64+64)

  const float* cost = lower ? cost2 : cost1;
  float* disp = lower ? disp_r2l : disp_l2r;
  float* csum = lower ? cs_r2l  : cs_l2r;
  float* raw  = out + (lower ? 2 : 3) * (H * W);
  const float* hb = cost + (size_t)h * W * W;

  scol[tid] = 0.f;
  __syncthreads();

  if (lower) {
    if (s < 4) process_rows<true,  false>(hb, h, s, lane, wid, disp, raw, scol);
    else       process_rows<true,  true >(hb, h, s, lane, wid, disp, raw, scol);
  } else {
    if (s < 4) process_rows<false, true >(hb, h, s, lane, wid, disp, raw, scol);
    else       process_rows<false, false>(hb, h, s, lane, wid, disp, raw, scol);
  }
  __syncthreads();

  // half-row blocks only contributed to their own half of scol
  const bool doMine = lower ? (s >= 4 || tid < 256)
                            : (s < 4  || tid >= 256);
  if (doMine) atomicAdd(&csum[h * W + tid], scol[tid]);
}

// ---------------------------------------------------------------------------
// Closed-form hole fill (the W-step scan converges to this):
//   valid i            -> disp_ini[i]
//   invalid, valid p<i -> disp_ini[p] * (1+1e-4)^-(i-p)   (left-to-right pass)
//   invalid prefix     -> disp_ini[p0] * (1+1e-4)^-(p0-i) (right-to-left pass)
//   no valid in row    -> 0
// One wave per (pair, h) row.
// ---------------------------------------------------------------------------
__global__ __launch_bounds__(64) void fill_rows(
    const float* __restrict__ dispA, const float* __restrict__ csA,
    const float* __restrict__ dispB, const float* __restrict__ csB,
    float* __restrict__ out)
{
  __shared__ float xrow[W];
  const int pair = blockIdx.x >> 6;   // 0: ch0 (r2l disp, vm_left), 1: ch1
  const int h    = blockIdx.x & 63;
  const float* dsp = (pair ? dispB : dispA) + h * W;
  const float* cs  = (pair ? csB  : csA ) + h * W;
  float* o = out + pair * (H * W) + h * W;
  const int lane = threadIdx.x;
  const int j0 = lane * 8;

  float x[8];
  bool m[8];
  int incl[8];
  int run = -1, fv = W;
  #pragma unroll
  for (int k = 0; k < 8; k++) {
    x[k] = dsp[j0 + k];
    m[k] = cs[j0 + k] > 0.1f;
    xrow[j0 + k] = x[k];
    if (m[k]) { run = j0 + k; if (fv == W) fv = j0 + k; }
    incl[k] = run;
  }
  // inclusive max-scan across lanes of "last valid index in my segment"
  int v = run;
  #pragma unroll
  for (int off = 1; off < 64; off <<= 1) {
    const int tv = __shfl_up(v, off);
    if (lane >= off) v = max(v, tv);
  }
  int excl = __shfl_up(v, 1);
  if (lane == 0) excl = -1;
  // first valid index in the whole row
  int p0 = fv;
  #pragma unroll
  for (int off = 32; off; off >>= 1) p0 = min(p0, __shfl_xor(p0, off));
  __syncthreads();

  const float C2 = -1.4426229e-4f;  // -log2(1 + 1e-4)
  #pragma unroll
  for (int k = 0; k < 8; k++) {
    const int jj = j0 + k;
    float ov;
    if (m[k]) {
      ov = x[k];
    } else {
      const int p = max(excl, incl[k]);
      if (p >= 0)        ov = xrow[p]  * exp2f(C2 * (float)(jj - p));
      else if (p0 < W)   ov = xrow[p0] * exp2f(C2 * (float)(p0 - jj));
      else               ov = 0.f;
    }
    o[jj] = ov;
  }
}

extern "C" void kernel_launch(void* const* d_in, const int* in_sizes, int n_in,
                              void* d_out, int out_size, void* d_ws, size_t ws_size,
                              hipStream_t stream) {
  const float* cost1 = (const float*)d_in[0];  // -> att_l2r (triu)
  const float* cost2 = (const float*)d_in[1];  // -> att_r2l (tril)
  float* out = (float*)d_out;                  // [4, H, W]
  float* w = (float*)d_ws;
  float* disp_r2l_ini = w;                     // 32768 floats (from cost2)
  float* disp_l2r_ini = w + 32768;             // (from cost1)
  float* cs_l2r       = w + 65536;             // colsums of att_l2r -> vm_left
  float* cs_r2l       = w + 98304;             // colsums of att_r2l -> vm_right

  hipMemsetAsync(cs_l2r, 0, 2 * (size_t)H * W * sizeof(float), stream);

  attn_stats_all<<<2 * H * SPLIT, 512, 0, stream>>>(
      cost1, cost2, disp_r2l_ini, disp_l2r_ini, cs_r2l, cs_l2r, out);

  // ch0 = regress(att_r2l, vm_left); ch1 = regress(att_l2r, vm_right)
  fill_rows<<<2 * H, 64, 0, stream>>>(disp_r2l_ini, cs_l2r,
                                      disp_l2r_ini, cs_r2l, out);
}